// Round 3
// baseline (112.033 us; speedup 1.0000x reference)
//
#include <hip/hip_runtime.h>

// Fused Haar-feature + 1x1-conv MLP.
//
//   f = conv2d(x, 6 fixed 6x6 Haar kernels / 36, SAME pad (2,3))
//   h1 = relu(f @ w1^T + b1)   [6->32]
//   h2 = relu(h1 @ w2^T + b2)  [32->16]
//   out = h2 @ w3^T + b3       [16->2]
//
// Haar kernels are separable (row (x) col from {ones, s=[+++---], t=[++--++]}),
// so a horizontal pass gives streams A(box), S(s), T(t) and vertical combines
// give all 6 features. The 1/36 normalization is folded into w1 (prep kernel).
//
// Round-3 changes vs round-2 (78.9 us, VGPR=48, accvgpr shuffling):
//  * amdgpu_waves_per_eu(4,4): pin the allocator to a 128-VGPR budget (4
//    waves/EU) so it stops splitting the live set into AGPRs. Round 2 showed
//    launch_bounds' min-waves arg alone does NOT stop the high-occupancy
//    squeeze (VGPR stayed 48 -> ~5 inst per layer-2 FMA).
//  * Process the 4 pixels as TWO sequential pixel-pairs: peak live set
//    ~90 floats (A/S/T 27 + f2 12 + h2 32 + temps) fits the 128 budget.
//  * __builtin_elementwise_fma on float2 everywhere in the MLP to guarantee
//    fma<2 x float> -> v_pk_fma_f32 (the 157 TF packed-fp32 path).

typedef float v2f __attribute__((ext_vector_type(2)));

#define TW 64
#define TH 16

// Pack weights into d_ws:
//   ws[0   .. 255]: pw1[m][0..7] = {w1[m][0..5]/36, b1[m], 0}   (m = 0..31)
//   ws[256 .. 767]: pw2t[m][o]   = w2[o][m]                      (contiguous in o)
__global__ __launch_bounds__(512) void haar_prep(const float* __restrict__ w1,
                                                 const float* __restrict__ b1,
                                                 const float* __restrict__ w2,
                                                 float* __restrict__ ws) {
  int t = threadIdx.x;
  if (t < 256) {
    int m = t >> 3, k = t & 7;
    float v = 0.f;
    if (k < 6) v = w1[m * 6 + k] * (1.0f / 36.0f);
    else if (k == 6) v = b1[m];
    ws[t] = v;
  }
  int m = t >> 4, o = t & 15;
  ws[256 + t] = w2[o * 32 + m];
}

__global__ __launch_bounds__(256)
__attribute__((amdgpu_waves_per_eu(4, 4)))
void haar_main(const float* __restrict__ x,
               const float* __restrict__ ws,
               const float* __restrict__ b2,
               const float* __restrict__ w3,
               const float* __restrict__ b3,
               float* __restrict__ out) {
  // input halo tile: (TH+5) x (TW+5), row stride padded to 72 floats
  __shared__ float tile[TH + 5][72];

  const int tid = threadIdx.x;
  const int bc = blockIdx.x * TW;   // output col base
  const int br = blockIdx.y * TH;   // output row base
  const int b  = blockIdx.z;
  const float* xb = x + (size_t)b * (512 * 512);

  // ---- stage input tile (zero-pad OOB); SAME pad: lo=2, hi=3 ----
  #pragma unroll
  for (int e = 0; e < 6; ++e) {
    int idx = tid + e * 256;
    if (idx < (TH + 5) * (TW + 5)) {
      int r = idx / (TW + 5);
      int c = idx - r * (TW + 5);
      int gr = br - 2 + r, gc = bc - 2 + c;
      float v = 0.f;
      if ((unsigned)gr < 512u && (unsigned)gc < 512u) v = xb[gr * 512 + gc];
      tile[r][c] = v;
    }
  }
  __syncthreads();

  const int jl = tid & 63;          // col within tile
  const int r0 = (tid >> 6) * 4;    // first of 4 output rows this thread owns

  // ---- horizontal pass: 9 rows of A/S/T for this thread's column ----
  float A[9], S[9], T[9];
  #pragma unroll
  for (int rr = 0; rr < 9; ++rr) {
    const float* row = &tile[r0 + rr][jl];
    float x0 = row[0], x1 = row[1], x2 = row[2];
    float x3 = row[3], x4 = row[4], x5 = row[5];
    float p01 = x0 + x1, p23 = x2 + x3, p45 = x4 + x5;
    A[rr] = p01 + p23 + p45;          // box
    T[rr] = p01 - p23 + p45;          // [+,+,-,-,+,+]
    S[rr] = (p01 + x2) - (x3 + p45);  // [+,+,+,-,-,-]
  }

  const int colg = bc + jl;

  // ---- two sequential pixel-pairs (keeps live set ~90 regs) ----
  #pragma unroll 1
  for (int pp = 0; pp < 2; ++pp) {
    // vertical combines -> 6 features for pixels {2pp, 2pp+1}, packed
    v2f f2[6];
    {
      float fs[6][2];
      #pragma unroll
      for (int q = 0; q < 2; ++q) {
        int p = pp * 2 + q;
        float ta = A[p] + A[p + 1] + A[p + 2];
        float tb = A[p + 3] + A[p + 4] + A[p + 5];
        fs[0][q] = ta + tb;                 // box (x) box
        fs[1][q] = ta - tb;                 // s-rows (x) box
        float q01 = A[p] + A[p + 1], q23 = A[p + 2] + A[p + 3], q45 = A[p + 4] + A[p + 5];
        fs[3][q] = q01 - q23 + q45;         // t-rows (x) box
        float sa = S[p] + S[p + 1] + S[p + 2];
        float sb = S[p + 3] + S[p + 4] + S[p + 5];
        fs[2][q] = sa + sb;                 // box (x) s-cols
        fs[5][q] = sa - sb;                 // s-rows (x) s-cols (checker)
        fs[4][q] = ((T[p] + T[p + 1]) + (T[p + 2] + T[p + 3])) + (T[p + 4] + T[p + 5]);
      }
      #pragma unroll
      for (int i = 0; i < 6; ++i) f2[i] = (v2f){fs[i][0], fs[i][1]};
    }

    // MLP: stream layer1 -> layer2 accumulation (packed fp32)
    v2f h2[16];
    #pragma unroll
    for (int o = 0; o < 16; ++o) {
      float bv = b2[o];
      h2[o] = (v2f){bv, bv};
    }

    #pragma unroll 2
    for (int m = 0; m < 32; ++m) {
      const float* pw1 = ws + m * 8;          // uniform -> s_load_dwordx8
      v2f a = (v2f){pw1[6], pw1[6]};
      a = __builtin_elementwise_fma((v2f){pw1[0], pw1[0]}, f2[0], a);
      a = __builtin_elementwise_fma((v2f){pw1[1], pw1[1]}, f2[1], a);
      a = __builtin_elementwise_fma((v2f){pw1[2], pw1[2]}, f2[2], a);
      a = __builtin_elementwise_fma((v2f){pw1[3], pw1[3]}, f2[3], a);
      a = __builtin_elementwise_fma((v2f){pw1[4], pw1[4]}, f2[4], a);
      a = __builtin_elementwise_fma((v2f){pw1[5], pw1[5]}, f2[5], a);
      v2f t = __builtin_elementwise_max(a, (v2f){0.f, 0.f});
      const float* pw2 = ws + 256 + m * 16;   // uniform -> s_load_dwordx16
      #pragma unroll
      for (int o = 0; o < 16; ++o)
        h2[o] = __builtin_elementwise_fma((v2f){pw2[o], pw2[o]}, t, h2[o]);
    }

    // layer3 + store for this pair
    v2f acc0 = (v2f){b3[0], b3[0]};
    v2f acc1 = (v2f){b3[1], b3[1]};
    #pragma unroll
    for (int o = 0; o < 16; ++o) {
      v2f r = __builtin_elementwise_max(h2[o], (v2f){0.f, 0.f});
      acc0 = __builtin_elementwise_fma((v2f){w3[o], w3[o]}, r, acc0);
      acc1 = __builtin_elementwise_fma((v2f){w3[16 + o], w3[16 + o]}, r, acc1);
    }

    const int row = br + r0 + pp * 2;
    size_t base0 = (((size_t)(b * 2 + 0) * 512) + row) * 512 + colg;
    size_t base1 = (((size_t)(b * 2 + 1) * 512) + row) * 512 + colg;
    out[base0]       = acc0.x;
    out[base0 + 512] = acc0.y;
    out[base1]       = acc1.x;
    out[base1 + 512] = acc1.y;
  }
}

extern "C" void kernel_launch(void* const* d_in, const int* in_sizes, int n_in,
                              void* d_out, int out_size, void* d_ws, size_t ws_size,
                              hipStream_t stream) {
  const float* x  = (const float*)d_in[0];
  const float* w1 = (const float*)d_in[1];
  const float* b1 = (const float*)d_in[2];
  const float* w2 = (const float*)d_in[3];
  const float* b2 = (const float*)d_in[4];
  const float* w3 = (const float*)d_in[5];
  const float* b3 = (const float*)d_in[6];
  float* out = (float*)d_out;
  float* ws  = (float*)d_ws;

  haar_prep<<<1, 512, 0, stream>>>(w1, b1, w2, ws);

  dim3 grid(512 / TW, 512 / TH, 16);   // (8, 32, 16)
  haar_main<<<grid, 256, 0, stream>>>(x, ws, b2, w3, b3, out);
}

// Round 4
// 87.405 us; speedup vs baseline: 1.2818x; 1.2818x over previous
//
#include <hip/hip_runtime.h>

// Fused Haar-feature + 1x1-conv MLP.
//
//   f = conv2d(x, 6 fixed 6x6 Haar kernels / 36, SAME pad (2,3))
//   h1 = relu(f @ w1^T + b1)   [6->32]
//   h2 = relu(h1 @ w2^T + b2)  [32->16]
//   out = h2 @ w3^T + b3       [16->2]
//
// Haar kernels are separable (row (x) col from {ones, s=[+++---], t=[++--++]}),
// so a horizontal pass gives streams A(box), S(s), T(t) and vertical combines
// give all 6 features. The 1/36 normalization is folded into w1 (prep kernel).
//
// Round-4 analysis: fp32 peak 157.3 TF on gfx950 = SCALAR v_fma_f32 rate
// (SIMD-32; m07 measured scalar fma 103 TF > 78.6 SIMD-16 ceiling). There is
// no packed-fp32 throughput gain on CDNA4 -> drop all v2f/pk attempts.
// Roofline: 770 FMA/px * 4.19M px = 3.23 G FMA -> ~41 us @ 100% VALU.
// Rounds 1-3 lost ~30 us to register spilling (VGPR capped at 48-52, h2
// accumulators bounced through AGPRs/LDS). Fix: ONE pixel's MLP at a time
// (h2[16] scalars), peak live ~59 regs -> fits the 64-VGPR/8-wave budget
// naturally. No waves_per_eu attributes (round 3 showed they cause LDS spill).

#define TW 64
#define TH 16

// ws layout: 32 rows of 24 floats (96 B stride):
//   row m: [0..5] = w1[m][0..5]/36, [6] = b1[m], [7] = pad,
//          [8..23] = w2[o][m] for o = 0..15  (transposed w2)
// => per m-iteration: one s_load_dwordx8 + one s_load_dwordx16.
__global__ __launch_bounds__(768) void haar_prep(const float* __restrict__ w1,
                                                 const float* __restrict__ b1,
                                                 const float* __restrict__ w2,
                                                 float* __restrict__ ws) {
  int t = threadIdx.x;            // 0..767
  int m = t / 24, j = t % 24;
  float v = 0.f;
  if (j < 6)       v = w1[m * 6 + j] * (1.0f / 36.0f);
  else if (j == 6) v = b1[m];
  else if (j >= 8) v = w2[(j - 8) * 32 + m];
  ws[m * 24 + j] = v;
}

__global__ __launch_bounds__(256) void haar_main(const float* __restrict__ x,
                                                 const float* __restrict__ ws,
                                                 const float* __restrict__ b2,
                                                 const float* __restrict__ w3,
                                                 const float* __restrict__ b3,
                                                 float* __restrict__ out) {
  // input halo tile: (TH+5) x (TW+5), row stride padded to 72 floats
  __shared__ float tile[TH + 5][72];

  const int tid = threadIdx.x;
  const int bc = blockIdx.x * TW;   // output col base
  const int br = blockIdx.y * TH;   // output row base
  const int b  = blockIdx.z;
  const float* xb = x + (size_t)b * (512 * 512);

  // ---- stage input tile (zero-pad OOB); SAME pad: lo=2, hi=3 ----
  #pragma unroll
  for (int e = 0; e < 6; ++e) {
    int idx = tid + e * 256;
    if (idx < (TH + 5) * (TW + 5)) {
      int r = idx / (TW + 5);
      int c = idx - r * (TW + 5);
      int gr = br - 2 + r, gc = bc - 2 + c;
      float v = 0.f;
      if ((unsigned)gr < 512u && (unsigned)gc < 512u) v = xb[gr * 512 + gc];
      tile[r][c] = v;
    }
  }
  __syncthreads();

  const int jl = tid & 63;          // col within tile
  const int r0 = (tid >> 6) * 4;    // first of 4 output rows this thread owns

  // ---- horizontal pass: 9 rows of A/S/T for this thread's column ----
  float A[9], S[9], T[9];
  #pragma unroll
  for (int rr = 0; rr < 9; ++rr) {
    const float* row = &tile[r0 + rr][jl];
    float x0 = row[0], x1 = row[1], x2 = row[2];
    float x3 = row[3], x4 = row[4], x5 = row[5];
    float p01 = x0 + x1, p23 = x2 + x3, p45 = x4 + x5;
    A[rr] = p01 + p23 + p45;          // box
    T[rr] = p01 - p23 + p45;          // [+,+,-,-,+,+]
    S[rr] = (p01 + x2) - (x3 + p45);  // [+,+,+,-,-,-]
  }

  // ---- vertical combines -> 6 features per pixel; A/S/T die here ----
  float f[4][6];
  #pragma unroll
  for (int p = 0; p < 4; ++p) {
    float ta = A[p] + A[p + 1] + A[p + 2];
    float tb = A[p + 3] + A[p + 4] + A[p + 5];
    f[p][0] = ta + tb;                 // box (x) box
    f[p][1] = ta - tb;                 // s-rows (x) box
    float q01 = A[p] + A[p + 1], q23 = A[p + 2] + A[p + 3], q45 = A[p + 4] + A[p + 5];
    f[p][3] = q01 - q23 + q45;         // t-rows (x) box
    float sa = S[p] + S[p + 1] + S[p + 2];
    float sb = S[p + 3] + S[p + 4] + S[p + 5];
    f[p][2] = sa + sb;                 // box (x) s-cols
    f[p][5] = sa - sb;                 // s-rows (x) s-cols (checker)
    f[p][4] = ((T[p] + T[p + 1]) + (T[p + 2] + T[p + 3])) + (T[p + 4] + T[p + 5]);
  }

  const int colg = bc + jl;

  // ---- MLP: one pixel at a time (h2[16] live, not [16][4]) ----
  #pragma unroll
  for (int p = 0; p < 4; ++p) {
    float h2[16];
    #pragma unroll
    for (int o = 0; o < 16; ++o) h2[o] = b2[o];   // uniform s_loads

    #pragma unroll 2
    for (int m = 0; m < 32; ++m) {
      const float* pm = ws + m * 24;              // uniform -> s_load x8 + x16
      float a = pm[6];
      a = fmaf(pm[0], f[p][0], a);
      a = fmaf(pm[1], f[p][1], a);
      a = fmaf(pm[2], f[p][2], a);
      a = fmaf(pm[3], f[p][3], a);
      a = fmaf(pm[4], f[p][4], a);
      a = fmaf(pm[5], f[p][5], a);
      a = fmaxf(a, 0.f);
      #pragma unroll
      for (int o = 0; o < 16; ++o) h2[o] = fmaf(pm[8 + o], a, h2[o]);
    }

    float acc0 = b3[0], acc1 = b3[1];
    #pragma unroll
    for (int o = 0; o < 16; ++o) {
      float r = fmaxf(h2[o], 0.f);
      acc0 = fmaf(w3[o], r, acc0);
      acc1 = fmaf(w3[16 + o], r, acc1);
    }

    const int row = br + r0 + p;
    out[((size_t)(b * 2 + 0) * 512 + row) * 512 + colg] = acc0;
    out[((size_t)(b * 2 + 1) * 512 + row) * 512 + colg] = acc1;
  }
}

extern "C" void kernel_launch(void* const* d_in, const int* in_sizes, int n_in,
                              void* d_out, int out_size, void* d_ws, size_t ws_size,
                              hipStream_t stream) {
  const float* x  = (const float*)d_in[0];
  const float* w1 = (const float*)d_in[1];
  const float* b1 = (const float*)d_in[2];
  const float* w2 = (const float*)d_in[3];
  const float* b2 = (const float*)d_in[4];
  const float* w3 = (const float*)d_in[5];
  const float* b3 = (const float*)d_in[6];
  float* out = (float*)d_out;
  float* ws  = (float*)d_ws;

  haar_prep<<<1, 768, 0, stream>>>(w1, b1, w2, ws);

  dim3 grid(512 / TW, 512 / TH, 16);   // (8, 32, 16)
  haar_main<<<grid, 256, 0, stream>>>(x, ws, b2, w3, b3, out);
}